// Round 10
// baseline (6874.728 us; speedup 1.0000x reference)
//
#include <hip/hip_runtime.h>
#include <math.h>

#define B_   4
#define T_   20000
#define SUB  20
#define ENO  2000
#define INO  500
#define HID  10
#define NCOS 24
#define TNO  200
#define NSL  25      // 20 E slices + 5 I slices, each 100 e wide
#define SLW  100     // slice width (floats)
#define BR   64      // t-rows per block
#define SST  101     // LDS row stride (+1 pad: conflict-free strided b128)
#define CWS  2048    // CwP slice stride (floats)

// ---------------- prep 1: softmax over subunit axis; CwP[z*2048 + s*100 + ep] = C*exp(scale); e2 = exp(W2)
__global__ __launch_bounds__(256) void prep1_kernel(
    const float* __restrict__ Ce_raw, const float* __restrict__ Ci_raw,
    const float* __restrict__ ge, const float* __restrict__ gi,
    const float* __restrict__ Es, const float* __restrict__ Is,
    const float* __restrict__ W2, const int* __restrict__ testp,
    float* __restrict__ outCe, float* __restrict__ outCi,
    float* __restrict__ CwP, float* __restrict__ e2)
{
  int idx = blockIdx.x * 256 + threadIdx.x;
  int test = *testp;
  float scale = test ? 10000.f : 1000.f;
  if (idx < ENO + INO) {
    const float* raw; const float* g; float* outC; int n, col, zbase; float sc;
    if (idx < ENO) { raw = Ce_raw; g = ge; outC = outCe; n = ENO; col = idx;       zbase = 0;  sc = expf(Es[col]); }
    else           { raw = Ci_raw; g = gi; outC = outCi; n = INO; col = idx - ENO; zbase = 20; sc = expf(Is[col]); }
    float v[SUB]; float m = -1e30f;
    #pragma unroll
    for (int s = 0; s < SUB; s++) {
      float x = raw[s * n + col];
      if (!test) x += g[s * n + col];
      x *= scale;
      v[s] = x; m = fmaxf(m, x);
    }
    float sum = 0.f;
    #pragma unroll
    for (int s = 0; s < SUB; s++) { v[s] = expf(v[s] - m); sum += v[s]; }
    float inv = 1.f / sum;
    int z = zbase + col / SLW, ep = col % SLW;
    #pragma unroll
    for (int s = 0; s < SUB; s++) {
      float c = v[s] * inv;
      outC[s * n + col] = c;
      CwP[(long)z * CWS + s * SLW + ep] = c * sc;
    }
  } else if (idx < ENO + INO + SUB * HID) {
    int j = idx - (ENO + INO);
    e2[j] = expf(W2[j]);
  }
}

// ---------------- prep 2: effective kernels Keff[src][s][h][d] = sum_k W[s*HID+h,k] * basis(k,d)
__global__ __launch_bounds__(256) void prep2_kernel(
    const float* __restrict__ We, const float* __restrict__ Wi, float* __restrict__ Keff)
{
  int idx = blockIdx.x * 256 + threadIdx.x;
  if (idx >= 2 * SUB * HID * TNO) return;
  int d   = idx % TNO;
  int sh  = (idx / TNO) % (SUB * HID);
  int src = idx / (TNO * SUB * HID);
  const float* W = src ? Wi : We;           // [SUB*HID][NCOS]
  const float PIF = 3.14159265358979323846f;
  float raw = 6.0f * logf((float)d + 1.0f + 1e-7f);
  float acc = 0.f;
  #pragma unroll
  for (int k = 0; k < NCOS; k++) {
    float ph = 1.57079632679489662f * (float)k;
    if (raw >= ph - PIF && raw <= ph + PIF) {
      acc += W[sh * NCOS + k] * (0.5f * cosf(raw - ph) + 0.5f);
    }
  }
  Keff[idx] = acc;
}

// ---------------- GEMM: syn[b][s][t] = sum_e S[b,t,e] * Cw[s,e]
// Proven-clean reg-staging skeleton (R2/R5 family; NO global_load_lds anywhere).
// Block = 64 t-rows, lane = row, wave w owns s 5w..5w+4. K = 25 slices of 100 e.
// Per slice: {barrier; ds_write staged regs; barrier; prefetch next slice -> regs;
// LDS-only compute}. The prefetch's vmcnt is waited at the NEXT iteration's ds_write,
// i.e. after ~1000cy of FMA -> HBM latency hidden in-wave; 4 blocks/CU adds TLP.
// sv: stride-101 b128 (2 lanes/bank = free). cw: wave-uniform LDS broadcast (free).
// No e-split -> no shuffle/bpermute reduce tail.
__global__ __launch_bounds__(256, 2) void gemm_syn_kernel(
    const float* __restrict__ S_e, const float* __restrict__ S_i,
    const float* __restrict__ CwP,
    float* __restrict__ synE, float* __restrict__ synI)
{
  const int b  = blockIdx.y;
  const int t0 = blockIdx.x * BR;
  __shared__ __align__(16) float sS[BR * SST];   // 25.9 KB
  __shared__ __align__(16) float sC[2000];       // 8 KB: [s][100]

  const int tid = threadIdx.x;
  const int l   = tid & 63;
  const int w   = tid >> 6;
  const int s0  = w * 5;
  int maxr = T_ - 1 - t0; if (maxr > BR - 1) maxr = BR - 1;

  const long baseE = ((long)(b * T_ + t0)) * ENO;
  const long baseI = ((long)(b * T_ + t0)) * INO;

  float4 vS[7];
  float4 vC0, vC1;
  float4 acc[5];
  #pragma unroll
  for (int j = 0; j < 5; j++) acc[j] = make_float4(0.f, 0.f, 0.f, 0.f);

  // ---- preload slice 0 into regs
  {
    const float* __restrict__ src = S_e + baseE;
    #pragma unroll
    for (int p = 0; p < 7; p++) {
      int u = tid + 256 * p;
      if (u < 1600) {
        int r = u / 25, k = u - 25 * r;
        if (r > maxr) r = maxr;
        vS[p] = *(const float4*)&src[(long)r * ENO + 4 * k];
      }
    }
    const float* __restrict__ csrc = CwP;
    vC0 = *(const float4*)&csrc[4 * tid];
    if (tid < 244) vC1 = *(const float4*)&csrc[4 * (tid + 256)];
  }

  for (int z = 0; z < NSL; z++) {
    __syncthreads();   // previous compute done before LDS overwrite
    // ---- commit staged regs -> LDS (vmcnt waits happen here, after prev compute)
    #pragma unroll
    for (int p = 0; p < 7; p++) {
      int u = tid + 256 * p;
      if (u < 1600) {
        int r = u / 25, k = u - 25 * r;   // r<64 always: bijective LDS slot
        *(float4*)&sS[r * SST + 4 * k] = vS[p];
      }
    }
    *(float4*)&sC[4 * tid] = vC0;
    if (tid < 244) *(float4*)&sC[4 * (tid + 256)] = vC1;
    __syncthreads();   // tile ready

    // ---- prefetch slice z+1 into regs; drains during compute below
    if (z + 1 < NSL) {
      const bool nE = (z + 1 < 20);
      const float* __restrict__ src = nE ? (S_e + baseE + (z + 1) * SLW)
                                         : (S_i + baseI + (z + 1 - 20) * SLW);
      const int rs = nE ? ENO : INO;
      #pragma unroll
      for (int p = 0; p < 7; p++) {
        int u = tid + 256 * p;
        if (u < 1600) {
          int r = u / 25, k = u - 25 * r;
          if (r > maxr) r = maxr;
          vS[p] = *(const float4*)&src[(long)r * rs + 4 * k];
        }
      }
      const float* __restrict__ csrc = CwP + (long)(z + 1) * CWS;
      vC0 = *(const float4*)&csrc[4 * tid];
      if (tid < 244) vC1 = *(const float4*)&csrc[4 * (tid + 256)];
    }

    // ---- compute slice z: LDS-only reads
    {
      const float* rowp = sS + l * SST;
      const float* cb   = sC + s0 * SLW;
      #pragma unroll
      for (int e4 = 0; e4 < 25; e4++) {
        float4 sv = *(const float4*)&rowp[4 * e4];
        #pragma unroll
        for (int j = 0; j < 5; j++) {
          float4 cw = *(const float4*)&cb[j * SLW + 4 * e4];   // broadcast
          acc[j].x += sv.x * cw.x; acc[j].y += sv.y * cw.y;
          acc[j].z += sv.z * cw.z; acc[j].w += sv.w * cw.w;
        }
      }
    }

    // ---- output at end of E (z==19) and end of I (z==24)
    if (z == 19 || z == 24) {
      float* __restrict__ dst = (z == 19) ? synE : synI;
      if (t0 + l < T_) {
        #pragma unroll
        for (int j = 0; j < 5; j++)
          dst[((long)b * SUB + s0 + j) * T_ + t0 + l]
              = acc[j].x + acc[j].y + acc[j].z + acc[j].w;
      }
      #pragma unroll
      for (int j = 0; j < 5; j++) acc[j] = make_float4(0.f, 0.f, 0.f, 0.f);
    }
  }
}

// ---------------- conv: pre[h,t] = sum_d Ke[h,d]*syn_e[t-d] + Ki[h,d]*syn_i[t-d]; tanh; combine over h
__global__ __launch_bounds__(256, 2) void conv_kernel(
    const float* __restrict__ synE, const float* __restrict__ synI,
    const float* __restrict__ Keff, const float* __restrict__ e2,
    const float* __restrict__ b1, float* __restrict__ sub_bst)
{
  const int chunk = blockIdx.x;       // 0..19
  const int s = blockIdx.y;
  const int b = blockIdx.z;
  const int cs = chunk * 1000;

  __shared__ __align__(16) float se[1200];
  __shared__ __align__(16) float si[1200];
  __shared__ __align__(16) float te[HID * TNO];
  __shared__ __align__(16) float ti[HID * TNO];
  __shared__ float se2[HID], sb[HID];

  const int tid = threadIdx.x;
  const float* __restrict__ pe = &synE[((long)b * SUB + s) * T_];
  const float* __restrict__ pin = &synI[((long)b * SUB + s) * T_];

  for (int i4 = tid; i4 < 300; i4 += 256) {
    int gt = cs - 200 + i4 * 4;
    float4 ve = make_float4(0.f, 0.f, 0.f, 0.f);
    float4 vi = make_float4(0.f, 0.f, 0.f, 0.f);
    if (gt >= 0) { ve = *(const float4*)&pe[gt]; vi = *(const float4*)&pin[gt]; }
    *(float4*)&se[i4 * 4] = ve;
    *(float4*)&si[i4 * 4] = vi;
  }
  const float* __restrict__ ke = &Keff[(long)s * HID * TNO];
  const float* __restrict__ ki = &Keff[((long)SUB + s) * HID * TNO];
  for (int i4 = tid; i4 < 500; i4 += 256) {
    *(float4*)&te[i4 * 4] = *(const float4*)&ke[i4 * 4];
    *(float4*)&ti[i4 * 4] = *(const float4*)&ki[i4 * 4];
  }
  if (tid < HID) { se2[tid] = e2[s * HID + tid]; sb[tid] = b1[s * HID + tid]; }
  __syncthreads();

  if (tid >= 250) return;
  const int lofs = 200 + 4 * tid;
  float so[4] = {0.f, 0.f, 0.f, 0.f};

  #pragma unroll
  for (int half = 0; half < 2; half++) {
    const int h0 = half * 5;
    float acc[5][4] = {};
    float we[8], wi[8];
    *(float4*)&we[4] = *(float4*)&se[lofs];
    *(float4*)&wi[4] = *(float4*)&si[lofs];
    for (int dstep = 0; dstep < 50; dstep++) {
      const int d0 = dstep * 4;
      *(float4*)&we[0] = *(float4*)&se[lofs - d0 - 4];
      *(float4*)&wi[0] = *(float4*)&si[lofs - d0 - 4];
      float4 tpe[5], tpi[5];
      #pragma unroll
      for (int h = 0; h < 5; h++) {
        tpe[h] = *(float4*)&te[(h0 + h) * TNO + d0];
        tpi[h] = *(float4*)&ti[(h0 + h) * TNO + d0];
      }
      #pragma unroll
      for (int dd = 0; dd < 4; dd++) {
        #pragma unroll
        for (int h = 0; h < 5; h++) {
          float tapeh = ((float*)&tpe[h])[dd];
          float tapih = ((float*)&tpi[h])[dd];
          #pragma unroll
          for (int j = 0; j < 4; j++) {
            acc[h][j] += tapeh * we[4 + j - dd];
            acc[h][j] += tapih * wi[4 + j - dd];
          }
        }
      }
      #pragma unroll
      for (int m = 0; m < 4; m++) { we[4 + m] = we[m]; wi[4 + m] = wi[m]; }
    }
    #pragma unroll
    for (int h = 0; h < 5; h++) {
      float eh = se2[h0 + h], bh = sb[h0 + h];
      #pragma unroll
      for (int j = 0; j < 4; j++) so[j] += eh * tanhf(acc[h][j] + bh);
    }
  }
  int t0 = cs + 4 * tid;
  *(float4*)&sub_bst[((long)b * SUB + s) * T_ + t0] = *(float4*)&so[0];
}

// ---------------- final: transpose sub_bst[b][s][t] -> sub_out[b][t][s], final[b][t] = sum_s + V_o
__global__ __launch_bounds__(256) void final_kernel(
    const float* __restrict__ sub_bst, const float* __restrict__ Vo,
    float* __restrict__ out_final, float* __restrict__ out_sub)
{
  int t = blockIdx.x * 256 + threadIdx.x;
  int b = blockIdx.y;
  if (t >= T_) return;
  float vo = Vo[0];
  float sum = 0.f;
  #pragma unroll
  for (int s = 0; s < SUB; s++) {
    float v = sub_bst[((long)b * SUB + s) * T_ + t];
    sum += v;
    out_sub[(((long)b * T_) + t) * SUB + s] = v;
  }
  out_final[(long)b * T_ + t] = sum + vo;
}

extern "C" void kernel_launch(void* const* d_in, const int* in_sizes, int n_in,
                              void* d_out, int out_size, void* d_ws, size_t ws_size,
                              hipStream_t stream)
{
  const float* S_e    = (const float*)d_in[0];
  const float* S_i    = (const float*)d_in[1];
  const int*   testp  = (const int*)d_in[3];
  const float* g_e    = (const float*)d_in[4];
  const float* g_i    = (const float*)d_in[5];
  const float* Es     = (const float*)d_in[6];
  const float* Is     = (const float*)d_in[7];
  const float* We     = (const float*)d_in[8];
  const float* Wi     = (const float*)d_in[9];
  const float* W2     = (const float*)d_in[10];
  const float* b1     = (const float*)d_in[11];
  const float* Ce_raw = (const float*)d_in[12];
  const float* Ci_raw = (const float*)d_in[13];
  const float* Vo     = (const float*)d_in[14];

  float* ws   = (float*)d_ws;
  float* CwP  = ws;                      // 25*2048 = 51200
  float* Keff = ws + 51200;              // 80000
  float* e2   = ws + 131200;             // 200
  float* synE = ws + 131400;             // 1,600,000
  float* synI = synE + 1600000;          // 1,600,000
  float* subb = synI + 1600000;          // 1,600,000

  float* out     = (float*)d_out;
  float* o_final = out;                  // 80,000
  float* o_sub   = out + 80000;          // 1,600,000
  float* o_Ce    = out + 1680000;        // 40,000
  float* o_Ci    = out + 1720000;        // 10,000

  prep1_kernel<<<11, 256, 0, stream>>>(Ce_raw, Ci_raw, g_e, g_i, Es, Is, W2, testp,
                                       o_Ce, o_Ci, CwP, e2);
  prep2_kernel<<<(2 * SUB * HID * TNO + 255) / 256, 256, 0, stream>>>(We, Wi, Keff);
  gemm_syn_kernel<<<dim3((T_ + BR - 1) / BR, B_), 256, 0, stream>>>(S_e, S_i, CwP, synE, synI);
  conv_kernel<<<dim3(20, SUB, B_), 256, 0, stream>>>(synE, synI, Keff, e2, b1, subb);
  final_kernel<<<dim3((T_ + 255) / 256, B_), 256, 0, stream>>>(subb, Vo, o_final, o_sub);
}

// Round 11
// 5960.688 us; speedup vs baseline: 1.1533x; 1.1533x over previous
//
#include <hip/hip_runtime.h>
#include <math.h>

#define B_   4
#define T_   20000
#define SUB  20
#define ENO  2000
#define INO  500
#define HID  10
#define NCOS 24
#define TNO  200
#define NSL  25      // 20 E slices + 5 I slices, each 100 e wide
#define SLW  100     // slice width (floats)
#define BR   64      // t-rows per block
#define CWS  2048    // CwP slice stride (floats)

#define AS1 __attribute__((address_space(1)))
#define AS3 __attribute__((address_space(3)))

// ---------------- prep 1: softmax over subunit axis; CwP[z*2048 + s*100 + ep] = C*exp(scale); e2 = exp(W2)
__global__ __launch_bounds__(256) void prep1_kernel(
    const float* __restrict__ Ce_raw, const float* __restrict__ Ci_raw,
    const float* __restrict__ ge, const float* __restrict__ gi,
    const float* __restrict__ Es, const float* __restrict__ Is,
    const float* __restrict__ W2, const int* __restrict__ testp,
    float* __restrict__ outCe, float* __restrict__ outCi,
    float* __restrict__ CwP, float* __restrict__ e2)
{
  int idx = blockIdx.x * 256 + threadIdx.x;
  int test = *testp;
  float scale = test ? 10000.f : 1000.f;
  if (idx < ENO + INO) {
    const float* raw; const float* g; float* outC; int n, col, zbase; float sc;
    if (idx < ENO) { raw = Ce_raw; g = ge; outC = outCe; n = ENO; col = idx;       zbase = 0;  sc = expf(Es[col]); }
    else           { raw = Ci_raw; g = gi; outC = outCi; n = INO; col = idx - ENO; zbase = 20; sc = expf(Is[col]); }
    float v[SUB]; float m = -1e30f;
    #pragma unroll
    for (int s = 0; s < SUB; s++) {
      float x = raw[s * n + col];
      if (!test) x += g[s * n + col];
      x *= scale;
      v[s] = x; m = fmaxf(m, x);
    }
    float sum = 0.f;
    #pragma unroll
    for (int s = 0; s < SUB; s++) { v[s] = expf(v[s] - m); sum += v[s]; }
    float inv = 1.f / sum;
    int z = zbase + col / SLW, ep = col % SLW;
    #pragma unroll
    for (int s = 0; s < SUB; s++) {
      float c = v[s] * inv;
      outC[s * n + col] = c;
      CwP[(long)z * CWS + s * SLW + ep] = c * sc;
    }
  } else if (idx < ENO + INO + SUB * HID) {
    int j = idx - (ENO + INO);
    e2[j] = expf(W2[j]);
  }
}

// ---------------- prep 2: effective kernels Keff[src][s][h][d] = sum_k W[s*HID+h,k] * basis(k,d)
__global__ __launch_bounds__(256) void prep2_kernel(
    const float* __restrict__ We, const float* __restrict__ Wi, float* __restrict__ Keff)
{
  int idx = blockIdx.x * 256 + threadIdx.x;
  if (idx >= 2 * SUB * HID * TNO) return;
  int d   = idx % TNO;
  int sh  = (idx / TNO) % (SUB * HID);
  int src = idx / (TNO * SUB * HID);
  const float* W = src ? Wi : We;           // [SUB*HID][NCOS]
  const float PIF = 3.14159265358979323846f;
  float raw = 6.0f * logf((float)d + 1.0f + 1e-7f);
  float acc = 0.f;
  #pragma unroll
  for (int k = 0; k < NCOS; k++) {
    float ph = 1.57079632679489662f * (float)k;
    if (raw >= ph - PIF && raw <= ph + PIF) {
      acc += W[sh * NCOS + k] * (0.5f * cosf(raw - ph) + 0.5f);
    }
  }
  Keff[idx] = acc;
}

// ---------------- GEMM: syn[b][s][t] = sum_e S[b,t,e] * Cw[s,e]
// R6-clean shape, single-buffered, with BOTH tiles staged via global_load_lds so the
// compute phase is LDS-only (one vmcnt drain per slice at the barrier).
// ANTI-PATHOLOGY: the slice loop bound is RUNTIME (nsl arg) so hipcc cannot fully
// unroll + cross-iteration-hoist (the R7-R10 scratch explosion); zero cross-iteration
// register state except acc[5].
// Block = 64 t-rows, lane = row, wave w owns s 5w..5w+4.
// sv: stride-100 b128 -> perfectly distributed 8 words/bank (R6 measured 0 conflicts).
// cw: wave-uniform broadcast b128 (free). LDS 33.6 KB -> 4 blocks/CU; TLP hides drains.
__global__ __launch_bounds__(256, 2) void gemm_syn_kernel(
    const float* __restrict__ S_e, const float* __restrict__ S_i,
    const float* __restrict__ CwP,
    float* __restrict__ synE, float* __restrict__ synI, int nsl)
{
  const int b  = blockIdx.y;
  const int t0 = blockIdx.x * BR;
  __shared__ __align__(16) float sS[BR * SLW];   // 25.6 KB, linear rows stride 100
  __shared__ __align__(16) float sC[CWS];        // 8 KB: [s][100] (+ pad, never read)

  const int tid = threadIdx.x;
  const int l   = tid & 63;
  const int w   = tid >> 6;
  const int s0  = w * 5;
  int maxr = T_ - 1 - t0; if (maxr > BR - 1) maxr = BR - 1;

  const long baseE = ((long)(b * T_ + t0)) * ENO;
  const long baseI = ((long)(b * T_ + t0)) * INO;

  float4 acc[5];
  #pragma unroll
  for (int j = 0; j < 5; j++) acc[j] = make_float4(0.f, 0.f, 0.f, 0.f);

  for (int z = 0; z < nsl; z++) {          // runtime bound: no full unroll
    const bool isE = (z < 20);
    const float* __restrict__ src  = isE ? (S_e + baseE + z * SLW)
                                         : (S_i + baseI + (z - 20) * SLW);
    const int rs = isE ? ENO : INO;
    const float* __restrict__ csrc = CwP + (long)z * CWS;

    // stage S slice: 25 chunks of 64 float4, direct global->LDS (linear dest)
    #pragma unroll
    for (int p = 0; p < 7; p++) {
      int c = w + 4 * p;
      if (c < 25) {
        int u = 64 * c + l;
        int r = u / 25, k = u - 25 * r;
        if (r > maxr) r = maxr;
        __builtin_amdgcn_global_load_lds(
            (const AS1 void*)(src + (long)r * rs + 4 * k),
            (AS3 void*)(sS + 256 * c), 16, 0, 0);
      }
    }
    // stage Cw slice: 8 chunks (500 f4 + dup tail)
    #pragma unroll
    for (int p = 0; p < 2; p++) {
      int c = w + 4 * p;
      int u = 64 * c + l;
      if (u > 499) u = 499;
      __builtin_amdgcn_global_load_lds(
          (const AS1 void*)(csrc + 4 * u),
          (AS3 void*)(sC + 256 * c), 16, 0, 0);
    }
    __syncthreads();   // single vmcnt drain; tiles ready

    // compute slice z: LDS-only reads
    {
      const float* rowp = sS + l * SLW;
      const float* cb   = sC + s0 * SLW;
      #pragma unroll
      for (int e4 = 0; e4 < 25; e4++) {
        float4 sv = *(const float4*)&rowp[4 * e4];
        #pragma unroll
        for (int j = 0; j < 5; j++) {
          float4 cw = *(const float4*)&cb[j * SLW + 4 * e4];   // broadcast
          acc[j].x += sv.x * cw.x; acc[j].y += sv.y * cw.y;
          acc[j].z += sv.z * cw.z; acc[j].w += sv.w * cw.w;
        }
      }
    }

    // output at end of E (z==19) and end of I (z==24)
    if (z == 19 || z == 24) {
      float* __restrict__ dst = (z == 19) ? synE : synI;
      if (t0 + l < T_) {
        #pragma unroll
        for (int j = 0; j < 5; j++)
          dst[((long)b * SUB + s0 + j) * T_ + t0 + l]
              = acc[j].x + acc[j].y + acc[j].z + acc[j].w;
      }
      #pragma unroll
      for (int j = 0; j < 5; j++) acc[j] = make_float4(0.f, 0.f, 0.f, 0.f);
    }
    __syncthreads();   // all LDS reads done before next slice's staging overwrites
  }
}

// ---------------- conv: pre[h,t] = sum_d Ke[h,d]*syn_e[t-d] + Ki[h,d]*syn_i[t-d]; tanh; combine over h
__global__ __launch_bounds__(256, 2) void conv_kernel(
    const float* __restrict__ synE, const float* __restrict__ synI,
    const float* __restrict__ Keff, const float* __restrict__ e2,
    const float* __restrict__ b1, float* __restrict__ sub_bst)
{
  const int chunk = blockIdx.x;       // 0..19
  const int s = blockIdx.y;
  const int b = blockIdx.z;
  const int cs = chunk * 1000;

  __shared__ __align__(16) float se[1200];
  __shared__ __align__(16) float si[1200];
  __shared__ __align__(16) float te[HID * TNO];
  __shared__ __align__(16) float ti[HID * TNO];
  __shared__ float se2[HID], sb[HID];

  const int tid = threadIdx.x;
  const float* __restrict__ pe = &synE[((long)b * SUB + s) * T_];
  const float* __restrict__ pin = &synI[((long)b * SUB + s) * T_];

  for (int i4 = tid; i4 < 300; i4 += 256) {
    int gt = cs - 200 + i4 * 4;
    float4 ve = make_float4(0.f, 0.f, 0.f, 0.f);
    float4 vi = make_float4(0.f, 0.f, 0.f, 0.f);
    if (gt >= 0) { ve = *(const float4*)&pe[gt]; vi = *(const float4*)&pin[gt]; }
    *(float4*)&se[i4 * 4] = ve;
    *(float4*)&si[i4 * 4] = vi;
  }
  const float* __restrict__ ke = &Keff[(long)s * HID * TNO];
  const float* __restrict__ ki = &Keff[((long)SUB + s) * HID * TNO];
  for (int i4 = tid; i4 < 500; i4 += 256) {
    *(float4*)&te[i4 * 4] = *(const float4*)&ke[i4 * 4];
    *(float4*)&ti[i4 * 4] = *(const float4*)&ki[i4 * 4];
  }
  if (tid < HID) { se2[tid] = e2[s * HID + tid]; sb[tid] = b1[s * HID + tid]; }
  __syncthreads();

  if (tid >= 250) return;
  const int lofs = 200 + 4 * tid;
  float so[4] = {0.f, 0.f, 0.f, 0.f};

  #pragma unroll
  for (int half = 0; half < 2; half++) {
    const int h0 = half * 5;
    float acc[5][4] = {};
    float we[8], wi[8];
    *(float4*)&we[4] = *(float4*)&se[lofs];
    *(float4*)&wi[4] = *(float4*)&si[lofs];
    for (int dstep = 0; dstep < 50; dstep++) {
      const int d0 = dstep * 4;
      *(float4*)&we[0] = *(float4*)&se[lofs - d0 - 4];
      *(float4*)&wi[0] = *(float4*)&si[lofs - d0 - 4];
      float4 tpe[5], tpi[5];
      #pragma unroll
      for (int h = 0; h < 5; h++) {
        tpe[h] = *(float4*)&te[(h0 + h) * TNO + d0];
        tpi[h] = *(float4*)&ti[(h0 + h) * TNO + d0];
      }
      #pragma unroll
      for (int dd = 0; dd < 4; dd++) {
        #pragma unroll
        for (int h = 0; h < 5; h++) {
          float tapeh = ((float*)&tpe[h])[dd];
          float tapih = ((float*)&tpi[h])[dd];
          #pragma unroll
          for (int j = 0; j < 4; j++) {
            acc[h][j] += tapeh * we[4 + j - dd];
            acc[h][j] += tapih * wi[4 + j - dd];
          }
        }
      }
      #pragma unroll
      for (int m = 0; m < 4; m++) { we[4 + m] = we[m]; wi[4 + m] = wi[m]; }
    }
    #pragma unroll
    for (int h = 0; h < 5; h++) {
      float eh = se2[h0 + h], bh = sb[h0 + h];
      #pragma unroll
      for (int j = 0; j < 4; j++) so[j] += eh * tanhf(acc[h][j] + bh);
    }
  }
  int t0 = cs + 4 * tid;
  *(float4*)&sub_bst[((long)b * SUB + s) * T_ + t0] = *(float4*)&so[0];
}

// ---------------- final: transpose sub_bst[b][s][t] -> sub_out[b][t][s], final[b][t] = sum_s + V_o
__global__ __launch_bounds__(256) void final_kernel(
    const float* __restrict__ sub_bst, const float* __restrict__ Vo,
    float* __restrict__ out_final, float* __restrict__ out_sub)
{
  int t = blockIdx.x * 256 + threadIdx.x;
  int b = blockIdx.y;
  if (t >= T_) return;
  float vo = Vo[0];
  float sum = 0.f;
  #pragma unroll
  for (int s = 0; s < SUB; s++) {
    float v = sub_bst[((long)b * SUB + s) * T_ + t];
    sum += v;
    out_sub[(((long)b * T_) + t) * SUB + s] = v;
  }
  out_final[(long)b * T_ + t] = sum + vo;
}

extern "C" void kernel_launch(void* const* d_in, const int* in_sizes, int n_in,
                              void* d_out, int out_size, void* d_ws, size_t ws_size,
                              hipStream_t stream)
{
  const float* S_e    = (const float*)d_in[0];
  const float* S_i    = (const float*)d_in[1];
  const int*   testp  = (const int*)d_in[3];
  const float* g_e    = (const float*)d_in[4];
  const float* g_i    = (const float*)d_in[5];
  const float* Es     = (const float*)d_in[6];
  const float* Is     = (const float*)d_in[7];
  const float* We     = (const float*)d_in[8];
  const float* Wi     = (const float*)d_in[9];
  const float* W2     = (const float*)d_in[10];
  const float* b1     = (const float*)d_in[11];
  const float* Ce_raw = (const float*)d_in[12];
  const float* Ci_raw = (const float*)d_in[13];
  const float* Vo     = (const float*)d_in[14];

  float* ws   = (float*)d_ws;
  float* CwP  = ws;                      // 25*2048 = 51200
  float* Keff = ws + 51200;              // 80000
  float* e2   = ws + 131200;             // 200
  float* synE = ws + 131400;             // 1,600,000
  float* synI = synE + 1600000;          // 1,600,000
  float* subb = synI + 1600000;          // 1,600,000

  float* out     = (float*)d_out;
  float* o_final = out;                  // 80,000
  float* o_sub   = out + 80000;          // 1,600,000
  float* o_Ce    = out + 1680000;        // 40,000
  float* o_Ci    = out + 1720000;        // 10,000

  prep1_kernel<<<11, 256, 0, stream>>>(Ce_raw, Ci_raw, g_e, g_i, Es, Is, W2, testp,
                                       o_Ce, o_Ci, CwP, e2);
  prep2_kernel<<<(2 * SUB * HID * TNO + 255) / 256, 256, 0, stream>>>(We, Wi, Keff);
  gemm_syn_kernel<<<dim3((T_ + BR - 1) / BR, B_), 256, 0, stream>>>(S_e, S_i, CwP, synE, synI, NSL);
  conv_kernel<<<dim3(20, SUB, B_), 256, 0, stream>>>(synE, synI, Keff, e2, b1, subb);
  final_kernel<<<dim3((T_ + 255) / 256, B_), 256, 0, stream>>>(subb, Vo, o_final, o_sub);
}